// Round 6
// baseline (143.576 us; speedup 1.0000x reference)
//
#include <hip/hip_runtime.h>
#include <hip/hip_bf16.h>

// b=1, c=256, h=w=64 -> n=4096 pixels, 4 heads, hd=64, 32 groups x 8 ch.
// scale = hd^-0.5 * log2(e) = 0.18033688, folded into Wq (K0) and bq (K1
// epilogue) so attention softmax uses native v_exp_f32 (exp2) directly.
#define NPIX 4096
#define CCH  256
#define HD   64
#define GSIZE 32768   // 8 ch * 4096 pix per group

#define QSCALE 0.18033688f   // 0.125 * log2(e); softmax in base-2 domain

typedef __bf16 bf16x8 __attribute__((ext_vector_type(8)));
typedef __bf16 bf16x4 __attribute__((ext_vector_type(4)));
typedef __bf16 bf16x2 __attribute__((ext_vector_type(2)));
typedef float  f32x4  __attribute__((ext_vector_type(4)));
typedef unsigned int uint32x4 __attribute__((ext_vector_type(4)));

#define XPITCH 264   // X/F panel pitch (bf16) for K1/K3

#if __has_builtin(__builtin_amdgcn_exp2f)
#define EXP2(x) __builtin_amdgcn_exp2f(x)
#else
#define EXP2(x) __expf((x) * 0.6931471805599453f)
#endif

// MFMA 16x16x32_bf16 layouts (verified m89/m91):
//   A[m=lane&15][k=quad*8+j]; B[k=quad*8+j][n=lane&15]; C: row=quad*4+reg, col=lane&15

__device__ __forceinline__ unsigned pack_bf16x2(float lo, float hi)
{
    bf16x2 v;
    v[0] = (__bf16)lo;
    v[1] = (__bf16)hi;
    return __builtin_bit_cast(unsigned, v);
}

// ---------------------------------------------------------------------------
// K0: blocks 0..255: per-(group,1/8th) partial sums -> psum/pssq[256].
//     blocks 256..319: weight fp32->bf16 convert (Wq scaled by QSCALE).
// ---------------------------------------------------------------------------
__global__ __launch_bounds__(256) void stats_wconv(
    const float* __restrict__ X,
    const float* __restrict__ Wq, const float* __restrict__ Wk,
    const float* __restrict__ Wv, const float* __restrict__ Wp,
    float* __restrict__ psum, float* __restrict__ pssq, __bf16* __restrict__ Wb)
{
    const int bid = blockIdx.x, t = threadIdx.x;
    if (bid < 256) {
        const float* base = X + bid * 4096;   // (g = bid>>3, seg = bid&7)
        float sum = 0.f, ssq = 0.f;
        #pragma unroll
        for (int k = 0; k < 4; ++k) {
            float4 v = *(const float4*)(base + t * 4 + k * 1024);
            sum += v.x + v.y + v.z + v.w;
            ssq += v.x * v.x + v.y * v.y + v.z * v.z + v.w * v.w;
        }
        #pragma unroll
        for (int off = 1; off < 64; off <<= 1) {
            sum += __shfl_xor(sum, off);
            ssq += __shfl_xor(ssq, off);
        }
        __shared__ float red[2][4];
        const int wv = t >> 6;
        if ((t & 63) == 0) { red[0][wv] = sum; red[1][wv] = ssq; }
        __syncthreads();
        if (t == 0) {
            psum[bid] = red[0][0] + red[0][1] + red[0][2] + red[0][3];
            pssq[bid] = red[1][0] + red[1][1] + red[1][2] + red[1][3];
        }
    } else {
        const int j0 = (bid - 256) * 4096 + t * 16;
        const int m  = j0 >> 16;
        const float* W = (m == 0) ? Wq : (m == 1) ? Wk : (m == 2) ? Wv : Wp;
        const float sc = (m == 0) ? QSCALE : 1.f;
        const int off = j0 & 65535;
        #pragma unroll
        for (int k = 0; k < 4; ++k) {
            float4 v = *(const float4*)(W + off + k * 4);
            bf16x4 o;
            o[0] = (__bf16)(v.x * sc); o[1] = (__bf16)(v.y * sc);
            o[2] = (__bf16)(v.z * sc); o[3] = (__bf16)(v.w * sc);
            *(bf16x4*)(Wb + m * 65536 + off + k * 4) = o;
        }
    }
}

// ---------------------------------------------------------------------------
// K1: fused GroupNorm-apply + QKV MFMA GEMM. grid (64 pixblk, 6: z*2+och).
// (unchanged; qs = QSCALE)
// ---------------------------------------------------------------------------
__global__ __launch_bounds__(256) void gn_qkv(
    const float* __restrict__ X, const float* __restrict__ gamma,
    const float* __restrict__ beta,
    const float* __restrict__ psum, const float* __restrict__ pssq,
    const __bf16* __restrict__ Wb,
    const float* __restrict__ bq, const float* __restrict__ bk,
    const float* __restrict__ bv,
    __bf16* __restrict__ Qb, __bf16* __restrict__ Kb, __bf16* __restrict__ Vb)
{
    __shared__ __bf16 tile[64 * XPITCH];
    __shared__ float al[256], bl[256];

    const int t = threadIdx.x, lane = t & 63, wave = t >> 6;
    const int l16 = lane & 15, quad = lane >> 4;
    const int p0 = blockIdx.x * 64;
    const int z = blockIdx.y >> 1, och = blockIdx.y & 1;

    {
        const int g = t >> 3;
        float s = 0.f, q = 0.f;
        #pragma unroll
        for (int j = 0; j < 8; ++j) { s += psum[g * 8 + j]; q += pssq[g * 8 + j]; }
        const float mu  = s * (1.f / GSIZE);
        const float var = q * (1.f / GSIZE) - mu * mu;
        const float a = gamma[t] * rsqrtf(var + 1e-6f);
        al[t] = a;
        bl[t] = beta[t] - mu * a;
    }
    __syncthreads();

    #pragma unroll 4
    for (int i = 0; i < 16; ++i) {
        const int c4 = wave * 64 + i * 4;
        f32x4 a4 = *(const f32x4*)(al + c4);
        f32x4 b4 = *(const f32x4*)(bl + c4);
        bf16x4 pk;
        pk[0] = (__bf16)(X[(c4 + 0) * NPIX + p0 + lane] * a4[0] + b4[0]);
        pk[1] = (__bf16)(X[(c4 + 1) * NPIX + p0 + lane] * a4[1] + b4[1]);
        pk[2] = (__bf16)(X[(c4 + 2) * NPIX + p0 + lane] * a4[2] + b4[2]);
        pk[3] = (__bf16)(X[(c4 + 3) * NPIX + p0 + lane] * a4[3] + b4[3]);
        *(bf16x4*)(tile + lane * XPITCH + c4) = pk;
    }
    __syncthreads();

    const int pw = wave * 16;
    bf16x8 xf[8];
    #pragma unroll
    for (int kc = 0; kc < 8; ++kc)
        xf[kc] = *(const bf16x8*)(tile + (pw + l16) * XPITCH + kc * 32 + quad * 8);

    const __bf16* Wz = Wb + z * 65536;
    const float* bias = (z == 0) ? bq : (z == 1) ? bk : bv;

    if (z < 2) {
        const float qs = (z == 0) ? QSCALE : 1.f;
        __bf16* dst = (z == 0) ? Qb : Kb;
        #pragma unroll
        for (int grp = 0; grp < 2; ++grp) {
            f32x4 acc[4] = {};
            #pragma unroll
            for (int kc = 0; kc < 8; ++kc) {
                #pragma unroll
                for (int u = 0; u < 4; ++u) {
                    bf16x8 wf = *(const bf16x8*)(Wz + (och * 128 + (grp * 4 + u) * 16 + l16) * CCH + kc * 32 + quad * 8);
                    acc[u] = __builtin_amdgcn_mfma_f32_16x16x32_bf16(wf, xf[kc], acc[u], 0, 0, 0);
                }
            }
            #pragma unroll
            for (int u = 0; u < 4; ++u) {
                const int ot = och * 8 + grp * 4 + u;
                f32x4 bz = *(const f32x4*)(bias + och * 128 + (grp * 4 + u) * 16 + quad * 4);
                bf16x4 o;
                o[0] = (__bf16)(acc[u][0] + bz[0] * qs);
                o[1] = (__bf16)(acc[u][1] + bz[1] * qs);
                o[2] = (__bf16)(acc[u][2] + bz[2] * qs);
                o[3] = (__bf16)(acc[u][3] + bz[3] * qs);
                const int head = ot >> 2, dloc = (ot & 3) * 16 + quad * 4;
                *(bf16x4*)(dst + head * (NPIX * HD) + (p0 + pw + l16) * HD + dloc) = o;
            }
        }
    } else {
        #pragma unroll
        for (int grp = 0; grp < 2; ++grp) {
            f32x4 acc[4] = {};
            #pragma unroll
            for (int kc = 0; kc < 8; ++kc) {
                #pragma unroll
                for (int u = 0; u < 4; ++u) {
                    bf16x8 wf = *(const bf16x8*)(Wz + (och * 128 + (grp * 4 + u) * 16 + l16) * CCH + kc * 32 + quad * 8);
                    acc[u] = __builtin_amdgcn_mfma_f32_16x16x32_bf16(xf[kc], wf, acc[u], 0, 0, 0);
                }
            }
            #pragma unroll
            for (int u = 0; u < 4; ++u) {
                const int oc = och * 128 + (grp * 4 + u) * 16 + l16;
                const float bz = bias[oc];
                bf16x4 o;
                o[0] = (__bf16)(acc[u][0] + bz); o[1] = (__bf16)(acc[u][1] + bz);
                o[2] = (__bf16)(acc[u][2] + bz); o[3] = (__bf16)(acc[u][3] + bz);
                *(bf16x4*)(Vb + oc * NPIX + p0 + pw + quad * 4) = o;
            }
        }
    }
}

// ---------------------------------------------------------------------------
// K2 (R14): zero-LDS attention with EXPLICIT cross-tile software pipeline
// (T15 att[2]-style). R13 post-mortem: halving L2 traffic + line-fills nulled
// -> memory theories dead. Counters: MFMA ~450 + VALU ~700 of ~2925 cyc/tile
// -> ~60% dual-pipe-idle dependency gaps: the serial QK->exp/pack->PV
// alternation at 1 wave/SIMD, which the compiler provably does not pipeline
// across tiles (R12 null). R14: two named tile-contexts (A/B); body is
// straight-line (clamped tail indices, no branches = one scheduling region):
//   qk(B)          <- MFMA pipe      } overlap
//   exppack(A)     <- VALU/trans     }
//   pv(A); ldV(t+2->A)
//   exppack(B); qk(A=t+2)            } overlap; K(t+2) loaded 3 phases ago
//   pv(B); ldK/ldV(t+3->B)
// Instruction totals and all math/layouts byte-identical to R12 (green).
// ---------------------------------------------------------------------------
__global__ __launch_bounds__(256, 1) void attn_mfma(
    const __bf16* __restrict__ Qb, const __bf16* __restrict__ Kb,
    const __bf16* __restrict__ Vb, __bf16* __restrict__ Sb)
{
    __shared__ __align__(16) float co[4 * 64 * 68];  // 69632 B merge buffer
    __shared__ float cl[4 * 64];

    const int t = threadIdx.x, lane = t & 63, wave = t >> 6;
    const int l16 = lane & 15, quad = lane >> 4;

    const int bid  = blockIdx.x;
    const int head = (bid & 7) >> 1;                   // XCD-pair pinning
    const int qt   = ((bid >> 3) << 1) | (bid & 1);    // 0..63
    const int p0   = qt * 64;

    const __bf16* Qh = Qb + head * (NPIX * HD);
    const __bf16* Kh = Kb + head * (NPIX * HD) + (wave * 32 + l16) * HD + quad * 8;
    const __bf16* Vh = Vb + head * (HD * NPIX) + l16 * NPIX + wave * 32 + quad * 8;

    // Q B-frags for 64 shared rows: B[k=d][n=row16]
    bf16x8 qf[4][2];
    #pragma unroll
    for (int rt = 0; rt < 4; ++rt) {
        const __bf16* qp = Qh + (p0 + rt * 16 + l16) * HD + quad * 8;
        qf[rt][0] = *(const bf16x8*)(qp);
        qf[rt][1] = *(const bf16x8*)(qp + 32);
    }

    bf16x8 ones;
    #pragma unroll
    for (int j = 0; j < 8; ++j) ones[j] = (__bf16)1.0f;

    f32x4 l_acc[4] = {};
    f32x4 o_acc[4][4] = {};   // [dt][rt]

    // named tile contexts
    bf16x8 kA0, kA1, kA2, kA3, vA0, vA1, vA2, vA3;
    bf16x8 kB0, kB1, kB2, kB3, vB0, vB1, vB2, vB3;
    f32x4 sA0[4], sA1[4], sB0[4], sB1[4];
    bf16x8 bp[4];

    auto ldK = [&](int it, bf16x8& k0, bf16x8& k1, bf16x8& k2, bf16x8& k3) {
        const __bf16* kp = Kh + it * (128 * HD);
        k0 = *(const bf16x8*)(kp);
        k1 = *(const bf16x8*)(kp + 32);
        k2 = *(const bf16x8*)(kp + 16 * HD);
        k3 = *(const bf16x8*)(kp + 16 * HD + 32);
    };
    auto ldV = [&](int it, bf16x8& v0, bf16x8& v1, bf16x8& v2, bf16x8& v3) {
        const __bf16* vp = Vh + it * 128;
        v0 = *(const bf16x8*)(vp);
        v1 = *(const bf16x8*)(vp + 16 * NPIX);
        v2 = *(const bf16x8*)(vp + 32 * NPIX);
        v3 = *(const bf16x8*)(vp + 48 * NPIX);
    };
    // S^T = K Q^T : C(key_local = kt*16+quad*4+r, row = rt*16+l16)
    auto qk = [&](bf16x8 k0, bf16x8 k1, bf16x8 k2, bf16x8 k3,
                  f32x4 (&s0)[4], f32x4 (&s1)[4]) {
        #pragma unroll
        for (int rt = 0; rt < 4; ++rt) {
            f32x4 z = {0.f, 0.f, 0.f, 0.f};
            s0[rt] = __builtin_amdgcn_mfma_f32_16x16x32_bf16(k0, qf[rt][0], z, 0, 0, 0);
            s0[rt] = __builtin_amdgcn_mfma_f32_16x16x32_bf16(k1, qf[rt][1], s0[rt], 0, 0, 0);
            s1[rt] = __builtin_amdgcn_mfma_f32_16x16x32_bf16(k2, qf[rt][0], z, 0, 0, 0);
            s1[rt] = __builtin_amdgcn_mfma_f32_16x16x32_bf16(k3, qf[rt][1], s1[rt], 0, 0, 0);
        }
    };
    // P = 2^(S'), C-layout -> B-layout in-register (swap32 then swap16)
    auto exppack = [&](const f32x4 (&s0)[4], const f32x4 (&s1)[4]) {
        #pragma unroll
        for (int rt = 0; rt < 4; ++rt) {
            unsigned a0 = pack_bf16x2(EXP2(s0[rt][0]), EXP2(s0[rt][1]));
            unsigned a1 = pack_bf16x2(EXP2(s0[rt][2]), EXP2(s0[rt][3]));
            unsigned b0 = pack_bf16x2(EXP2(s1[rt][0]), EXP2(s1[rt][1]));
            unsigned b1 = pack_bf16x2(EXP2(s1[rt][2]), EXP2(s1[rt][3]));
            asm("v_permlane32_swap_b32 %0, %1" : "+v"(a0), "+v"(b0));
            asm("v_permlane32_swap_b32 %0, %1" : "+v"(a1), "+v"(b1));
            asm("v_permlane16_swap_b32 %0, %1" : "+v"(a0), "+v"(b0));
            asm("v_permlane16_swap_b32 %0, %1" : "+v"(a1), "+v"(b1));
            uint32x4 w;
            w[0] = a0; w[1] = a1; w[2] = b0; w[3] = b1;
            bp[rt] = __builtin_bit_cast(bf16x8, w);  // B[k=key32][n=row]
        }
    };
    auto pv = [&](bf16x8 v0, bf16x8 v1, bf16x8 v2, bf16x8 v3) {
        #pragma unroll
        for (int rt = 0; rt < 4; ++rt) {
            l_acc[rt] = __builtin_amdgcn_mfma_f32_16x16x32_bf16(ones, bp[rt], l_acc[rt], 0, 0, 0);
            o_acc[0][rt] = __builtin_amdgcn_mfma_f32_16x16x32_bf16(v0, bp[rt], o_acc[0][rt], 0, 0, 0);
            o_acc[1][rt] = __builtin_amdgcn_mfma_f32_16x16x32_bf16(v1, bp[rt], o_acc[1][rt], 0, 0, 0);
            o_acc[2][rt] = __builtin_amdgcn_mfma_f32_16x16x32_bf16(v2, bp[rt], o_acc[2][rt], 0, 0, 0);
            o_acc[3][rt] = __builtin_amdgcn_mfma_f32_16x16x32_bf16(v3, bp[rt], o_acc[3][rt], 0, 0, 0);
        }
    };

    // prologue: tiles 0,1 loaded; S(0) computed
    ldK(0, kA0, kA1, kA2, kA3);  ldV(0, vA0, vA1, vA2, vA3);
    ldK(1, kB0, kB1, kB2, kB3);  ldV(1, vB0, vB1, vB2, vB3);
    qk(kA0, kA1, kA2, kA3, sA0, sA1);

    #pragma unroll 1
    for (int it = 0; it < 32; it += 2) {
        // clamped tail indices: last iter redundantly re-loads/computes tile 31
        // (results unused) to keep the body branch-free = one scheduler region.
        const int n2 = (it + 2 < 32) ? it + 2 : 31;
        const int n3 = (it + 3 < 32) ? it + 3 : 31;

        qk(kB0, kB1, kB2, kB3, sB0, sB1);     // S(t+1)   [MFMA]
        ldK(n2, kA0, kA1, kA2, kA3);          // K(t+2) issue (kA free)
        exppack(sA0, sA1);                    // P(t)     [VALU — overlaps qk]
        pv(vA0, vA1, vA2, vA3);               // O += t
        ldV(n2, vA0, vA1, vA2, vA3);          // V(t+2) issue (vA free)
        exppack(sB0, sB1);                    // P(t+1)   [VALU]
        qk(kA0, kA1, kA2, kA3, sA0, sA1);     // S(t+2)   [K latency covered]
        pv(vB0, vB1, vB2, vB3);               // O += t+1
        ldK(n3, kB0, kB1, kB2, kB3);
        ldV(n3, vB0, vB1, vB2, vB3);
    }

    // ---- in-LDS 4-way key merge ----
    #pragma unroll
    for (int dt = 0; dt < 4; ++dt)
        #pragma unroll
        for (int rt = 0; rt < 4; ++rt)
            *(f32x4*)(co + wave * 4352 + (rt * 16 + l16) * 68 + dt * 16 + quad * 4) = o_acc[dt][rt];
    if (quad == 0) {
        #pragma unroll
        for (int rt = 0; rt < 4; ++rt)
            cl[wave * 64 + rt * 16 + l16] = l_acc[rt][0];
    }
    __syncthreads();

    {
        const int row = t >> 2, dc = (t & 3) * 16;
        const float l = cl[row] + cl[64 + row] + cl[128 + row] + cl[192 + row];
        const float inv = 1.f / l;
        f32x4 s[4];
        #pragma unroll
        for (int j = 0; j < 4; ++j) {
            s[j] = f32x4{0.f, 0.f, 0.f, 0.f};
            #pragma unroll
            for (int w = 0; w < 4; ++w)
                s[j] += *(const f32x4*)(co + w * 4352 + row * 68 + dc + j * 4);
        }
        bf16x8 o1, o2;
        #pragma unroll
        for (int j = 0; j < 4; ++j) {
            o1[j]     = (__bf16)(s[0][j] * inv);
            o1[j + 4] = (__bf16)(s[1][j] * inv);
            o2[j]     = (__bf16)(s[2][j] * inv);
            o2[j + 4] = (__bf16)(s[3][j] * inv);
        }
        __bf16* dst = Sb + (p0 + row) * CCH + head * HD + dc;
        *(bf16x8*)(dst)     = o1;
        *(bf16x8*)(dst + 8) = o2;
    }
}

// ---------------------------------------------------------------------------
// K3: proj bf16 MFMA GEMM + bias + residual, fp32 out [c][pix].
// (reverted to R12's proven Sb-based version)
// ---------------------------------------------------------------------------
__global__ __launch_bounds__(256) void gemm_proj(
    const __bf16* __restrict__ Sb, const __bf16* __restrict__ Wpb,
    const float* __restrict__ bias, const float* __restrict__ X,
    float* __restrict__ Out)
{
    __shared__ __bf16 Bs[32 * XPITCH];

    const int t = threadIdx.x, lane = t & 63, wave = t >> 6;
    const int l16 = lane & 15, quad = lane >> 4;
    const int p0  = blockIdx.x * 32;
    const int och = blockIdx.y;

    #pragma unroll
    for (int pg = 0; pg < 4; ++pg) {
        bf16x8 v = *(const bf16x8*)(Sb + t * NPIX + p0 + pg * 8);
        #pragma unroll
        for (int j = 0; j < 8; ++j)
            Bs[(pg * 8 + j) * XPITCH + t] = v[j];
    }
    __syncthreads();

    const int pixset = wave & 1, ocset = wave >> 1;
    bf16x8 af[8];
    #pragma unroll
    for (int kc = 0; kc < 8; ++kc)
        af[kc] = *(const bf16x8*)(Bs + (pixset * 16 + l16) * XPITCH + kc * 32 + quad * 8);

    #pragma unroll
    for (int u = 0; u < 4; ++u) {
        f32x4 acc = {};
        const int oc_t = och * 128 + ocset * 64 + u * 16;
        #pragma unroll
        for (int kc = 0; kc < 8; ++kc) {
            bf16x8 wf = *(const bf16x8*)(Wpb + (oc_t + l16) * CCH + kc * 32 + quad * 8);
            acc = __builtin_amdgcn_mfma_f32_16x16x32_bf16(af[kc], wf, acc, 0, 0, 0);
        }
        const int oc  = oc_t + l16;
        const int pix = p0 + pixset * 16 + quad * 4;
        const float bz = bias[oc];
        f32x4 r4 = *(const f32x4*)(X + oc * NPIX + pix);
        f32x4 y;
        y[0] = acc[0] + bz + r4[0];
        y[1] = acc[1] + bz + r4[1];
        y[2] = acc[2] + bz + r4[2];
        y[3] = acc[3] + bz + r4[3];
        *(f32x4*)(Out + oc * NPIX + pix) = y;
    }
}

// ---------------------------------------------------------------------------
extern "C" void kernel_launch(void* const* d_in, const int* in_sizes, int n_in,
                              void* d_out, int out_size, void* d_ws, size_t ws_size,
                              hipStream_t stream)
{
    const float* x     = (const float*)d_in[0];
    const float* gamma = (const float*)d_in[1];
    const float* beta  = (const float*)d_in[2];
    const float* Wq    = (const float*)d_in[3];
    const float* bq    = (const float*)d_in[4];
    const float* Wk    = (const float*)d_in[5];
    const float* bk    = (const float*)d_in[6];
    const float* Wv    = (const float*)d_in[7];
    const float* bv    = (const float*)d_in[8];
    const float* Wp    = (const float*)d_in[9];
    const float* bp    = (const float*)d_in[10];
    float* out = (float*)d_out;

    char* ws = (char*)d_ws;
    float*  psum = (float*)(ws);                // 1KB stats partial sums
    float*  pssq = (float*)(ws + 1024);         // 1KB
    __bf16* Wb   = (__bf16*)(ws + 65536);       // 512KB bf16 4x[256][256]
    __bf16* Qb   = (__bf16*)(ws + (1 << 20));   // 2MB bf16 [head][pix][64]
    __bf16* Kb   = (__bf16*)(ws + (3 << 20));   // 2MB bf16 [head][pix][64]
    __bf16* Vb   = (__bf16*)(ws + (5 << 20));   // 2MB bf16 [c][pix]
    __bf16* Sb   = (__bf16*)(ws + (7 << 20));   // 2MB bf16 flat F

    stats_wconv<<<320, 256, 0, stream>>>(x, Wq, Wk, Wv, Wp, psum, pssq, Wb);

    dim3 gq(64, 6);
    gn_qkv<<<gq, 256, 0, stream>>>(x, gamma, beta, psum, pssq, Wb,
                                   bq, bk, bv, Qb, Kb, Vb);

    attn_mfma<<<256, 256, 0, stream>>>(Qb, Kb, Vb, Sb);

    dim3 gp(128, 2);
    gemm_proj<<<gp, 256, 0, stream>>>(Sb, Wb + 3 * 65536, bp, x, out);
}

// Round 7
// 142.894 us; speedup vs baseline: 1.0048x; 1.0048x over previous
//
#include <hip/hip_runtime.h>
#include <hip/hip_bf16.h>

// b=1, c=256, h=w=64 -> n=4096 pixels, 4 heads, hd=64, 32 groups x 8 ch.
// scale = hd^-0.5 * log2(e) = 0.18033688, folded into Wq (K0) and bq (K1
// epilogue) so attention softmax uses native v_exp_f32 (exp2) directly.
#define NPIX 4096
#define CCH  256
#define HD   64
#define GSIZE 32768   // 8 ch * 4096 pix per group

#define QSCALE 0.18033688f   // 0.125 * log2(e); softmax in base-2 domain

typedef __bf16 bf16x8 __attribute__((ext_vector_type(8)));
typedef __bf16 bf16x4 __attribute__((ext_vector_type(4)));
typedef __bf16 bf16x2 __attribute__((ext_vector_type(2)));
typedef float  f32x4  __attribute__((ext_vector_type(4)));
typedef float  f32x16 __attribute__((ext_vector_type(16)));
typedef unsigned int uint32x4 __attribute__((ext_vector_type(4)));

#define XPITCH 264   // X/F panel pitch (bf16) for K1/K3

#if __has_builtin(__builtin_amdgcn_exp2f)
#define EXP2(x) __builtin_amdgcn_exp2f(x)
#else
#define EXP2(x) __expf((x) * 0.6931471805599453f)
#endif

// MFMA layouts:
//  16x16x32 (m89/m91-verified): A[m=l&15][k=quad*8+j]; B[k=quad*8+j][n=l&15];
//    C: row=quad*4+reg, col=l&15.
//  32x32x16 (C per m74/m101-verified; A/B by the same lane rule):
//    A[m=l&31][k=(l>>5)*8+j]; B[k=(l>>5)*8+j][n=l&31];
//    C: col=l&31, row=(reg&3)+8*(reg>>2)+4*(l>>5), reg 0..15.
// permlane32_swap semantics (verified against the hardware-green R9 kernel):
//    swap(a,b): a <- [a.lo32 | b.lo32], b <- [a.hi32 | b.hi32]  (per-lane col kept)

__device__ __forceinline__ unsigned pack_bf16x2(float lo, float hi)
{
    bf16x2 v;
    v[0] = (__bf16)lo;
    v[1] = (__bf16)hi;
    return __builtin_bit_cast(unsigned, v);
}

// ---------------------------------------------------------------------------
// K0: blocks 0..255: per-(group,1/8th) partial sums -> psum/pssq[256].
//     blocks 256..319: weight fp32->bf16 convert (Wq scaled by QSCALE).
// ---------------------------------------------------------------------------
__global__ __launch_bounds__(256) void stats_wconv(
    const float* __restrict__ X,
    const float* __restrict__ Wq, const float* __restrict__ Wk,
    const float* __restrict__ Wv, const float* __restrict__ Wp,
    float* __restrict__ psum, float* __restrict__ pssq, __bf16* __restrict__ Wb)
{
    const int bid = blockIdx.x, t = threadIdx.x;
    if (bid < 256) {
        const float* base = X + bid * 4096;   // (g = bid>>3, seg = bid&7)
        float sum = 0.f, ssq = 0.f;
        #pragma unroll
        for (int k = 0; k < 4; ++k) {
            float4 v = *(const float4*)(base + t * 4 + k * 1024);
            sum += v.x + v.y + v.z + v.w;
            ssq += v.x * v.x + v.y * v.y + v.z * v.z + v.w * v.w;
        }
        #pragma unroll
        for (int off = 1; off < 64; off <<= 1) {
            sum += __shfl_xor(sum, off);
            ssq += __shfl_xor(ssq, off);
        }
        __shared__ float red[2][4];
        const int wv = t >> 6;
        if ((t & 63) == 0) { red[0][wv] = sum; red[1][wv] = ssq; }
        __syncthreads();
        if (t == 0) {
            psum[bid] = red[0][0] + red[0][1] + red[0][2] + red[0][3];
            pssq[bid] = red[1][0] + red[1][1] + red[1][2] + red[1][3];
        }
    } else {
        const int j0 = (bid - 256) * 4096 + t * 16;
        const int m  = j0 >> 16;
        const float* W = (m == 0) ? Wq : (m == 1) ? Wk : (m == 2) ? Wv : Wp;
        const float sc = (m == 0) ? QSCALE : 1.f;
        const int off = j0 & 65535;
        #pragma unroll
        for (int k = 0; k < 4; ++k) {
            float4 v = *(const float4*)(W + off + k * 4);
            bf16x4 o;
            o[0] = (__bf16)(v.x * sc); o[1] = (__bf16)(v.y * sc);
            o[2] = (__bf16)(v.z * sc); o[3] = (__bf16)(v.w * sc);
            *(bf16x4*)(Wb + m * 65536 + off + k * 4) = o;
        }
    }
}

// ---------------------------------------------------------------------------
// K1: fused GroupNorm-apply + QKV MFMA GEMM. grid (64 pixblk, 6: z*2+och).
// (unchanged; qs = QSCALE)
// ---------------------------------------------------------------------------
__global__ __launch_bounds__(256) void gn_qkv(
    const float* __restrict__ X, const float* __restrict__ gamma,
    const float* __restrict__ beta,
    const float* __restrict__ psum, const float* __restrict__ pssq,
    const __bf16* __restrict__ Wb,
    const float* __restrict__ bq, const float* __restrict__ bk,
    const float* __restrict__ bv,
    __bf16* __restrict__ Qb, __bf16* __restrict__ Kb, __bf16* __restrict__ Vb)
{
    __shared__ __bf16 tile[64 * XPITCH];
    __shared__ float al[256], bl[256];

    const int t = threadIdx.x, lane = t & 63, wave = t >> 6;
    const int l16 = lane & 15, quad = lane >> 4;
    const int p0 = blockIdx.x * 64;
    const int z = blockIdx.y >> 1, och = blockIdx.y & 1;

    {
        const int g = t >> 3;
        float s = 0.f, q = 0.f;
        #pragma unroll
        for (int j = 0; j < 8; ++j) { s += psum[g * 8 + j]; q += pssq[g * 8 + j]; }
        const float mu  = s * (1.f / GSIZE);
        const float var = q * (1.f / GSIZE) - mu * mu;
        const float a = gamma[t] * rsqrtf(var + 1e-6f);
        al[t] = a;
        bl[t] = beta[t] - mu * a;
    }
    __syncthreads();

    #pragma unroll 4
    for (int i = 0; i < 16; ++i) {
        const int c4 = wave * 64 + i * 4;
        f32x4 a4 = *(const f32x4*)(al + c4);
        f32x4 b4 = *(const f32x4*)(bl + c4);
        bf16x4 pk;
        pk[0] = (__bf16)(X[(c4 + 0) * NPIX + p0 + lane] * a4[0] + b4[0]);
        pk[1] = (__bf16)(X[(c4 + 1) * NPIX + p0 + lane] * a4[1] + b4[1]);
        pk[2] = (__bf16)(X[(c4 + 2) * NPIX + p0 + lane] * a4[2] + b4[2]);
        pk[3] = (__bf16)(X[(c4 + 3) * NPIX + p0 + lane] * a4[3] + b4[3]);
        *(bf16x4*)(tile + lane * XPITCH + c4) = pk;
    }
    __syncthreads();

    const int pw = wave * 16;
    bf16x8 xf[8];
    #pragma unroll
    for (int kc = 0; kc < 8; ++kc)
        xf[kc] = *(const bf16x8*)(tile + (pw + l16) * XPITCH + kc * 32 + quad * 8);

    const __bf16* Wz = Wb + z * 65536;
    const float* bias = (z == 0) ? bq : (z == 1) ? bk : bv;

    if (z < 2) {
        const float qs = (z == 0) ? QSCALE : 1.f;
        __bf16* dst = (z == 0) ? Qb : Kb;
        #pragma unroll
        for (int grp = 0; grp < 2; ++grp) {
            f32x4 acc[4] = {};
            #pragma unroll
            for (int kc = 0; kc < 8; ++kc) {
                #pragma unroll
                for (int u = 0; u < 4; ++u) {
                    bf16x8 wf = *(const bf16x8*)(Wz + (och * 128 + (grp * 4 + u) * 16 + l16) * CCH + kc * 32 + quad * 8);
                    acc[u] = __builtin_amdgcn_mfma_f32_16x16x32_bf16(wf, xf[kc], acc[u], 0, 0, 0);
                }
            }
            #pragma unroll
            for (int u = 0; u < 4; ++u) {
                const int ot = och * 8 + grp * 4 + u;
                f32x4 bz = *(const f32x4*)(bias + och * 128 + (grp * 4 + u) * 16 + quad * 4);
                bf16x4 o;
                o[0] = (__bf16)(acc[u][0] + bz[0] * qs);
                o[1] = (__bf16)(acc[u][1] + bz[1] * qs);
                o[2] = (__bf16)(acc[u][2] + bz[2] * qs);
                o[3] = (__bf16)(acc[u][3] + bz[3] * qs);
                const int head = ot >> 2, dloc = (ot & 3) * 16 + quad * 4;
                *(bf16x4*)(dst + head * (NPIX * HD) + (p0 + pw + l16) * HD + dloc) = o;
            }
        }
    } else {
        #pragma unroll
        for (int grp = 0; grp < 2; ++grp) {
            f32x4 acc[4] = {};
            #pragma unroll
            for (int kc = 0; kc < 8; ++kc) {
                #pragma unroll
                for (int u = 0; u < 4; ++u) {
                    bf16x8 wf = *(const bf16x8*)(Wz + (och * 128 + (grp * 4 + u) * 16 + l16) * CCH + kc * 32 + quad * 8);
                    acc[u] = __builtin_amdgcn_mfma_f32_16x16x32_bf16(xf[kc], wf, acc[u], 0, 0, 0);
                }
            }
            #pragma unroll
            for (int u = 0; u < 4; ++u) {
                const int oc = och * 128 + (grp * 4 + u) * 16 + l16;
                const float bz = bias[oc];
                bf16x4 o;
                o[0] = (__bf16)(acc[u][0] + bz); o[1] = (__bf16)(acc[u][1] + bz);
                o[2] = (__bf16)(acc[u][2] + bz); o[3] = (__bf16)(acc[u][3] + bz);
                *(bf16x4*)(Vb + oc * NPIX + p0 + pw + quad * 4) = o;
            }
        }
    }
}

// ---------------------------------------------------------------------------
// K2 (R15): zero-LDS attention on 32x32x16 MFMA — half the instructions.
// R14 post-mortem: time tracks instruction count (R0->R9 win = deleting LDS
// instrs; R11/R12/R13 memory/occupancy/prefetch changes all null; R14 added
// instrs -> regressed). One lone-wave 16x16x32 MFMA = 16 cyc pipe; R12's
// 36 MFMA + ~130 VALU per tile is the cost. R15 per 128-key tile per wave:
//   QK: 8 mfma_32x32x16 (2 q-ntiles x 4 d-chunks), PV: 8 (2 dt x 2 nt x 2 kc)
//   l: in-register 15-add tree per ntile (replaces 4 ones-MFMA)
//   P relayout: 16 cvt_pk + 8 permlane32_swap (T12; no permlane16)
// ~124 instrs/tile vs ~175. Grid/key-split/merge/epilogue byte-identical to
// the green R9/R12 code.
// ---------------------------------------------------------------------------
__global__ __launch_bounds__(256, 1) void attn_mfma(
    const __bf16* __restrict__ Qb, const __bf16* __restrict__ Kb,
    const __bf16* __restrict__ Vb, __bf16* __restrict__ Sb)
{
    __shared__ __align__(16) float co[4 * 64 * 68];  // 69632 B merge buffer
    __shared__ float cl[4 * 64];

    const int t = threadIdx.x, lane = t & 63, wave = t >> 6;
    const int c31 = lane & 31, hi = lane >> 5;

    const int bid  = blockIdx.x;
    const int head = (bid & 7) >> 1;                   // XCD-pair pinning
    const int qt   = ((bid >> 3) << 1) | (bid & 1);    // 0..63
    const int p0   = qt * 64;

    // per-lane fragment bases (wave owns keys [wave*32,+32) of each 128-tile)
    const __bf16* Kl = Kb + head * (NPIX * HD) + (wave * 32 + c31) * HD + hi * 8;
    const __bf16* Vl = Vb + (head * HD + c31) * NPIX + wave * 32 + hi * 8;
    const __bf16* Qh = Qb + head * (NPIX * HD);

    // Q B-frags: B[k=d: c*16+hi*8+j][n=q: p0+nt*32+c31]
    bf16x8 qf[2][4];
    #pragma unroll
    for (int nt = 0; nt < 2; ++nt)
        #pragma unroll
        for (int c = 0; c < 4; ++c)
            qf[nt][c] = *(const bf16x8*)(Qh + (p0 + nt * 32 + c31) * HD + c * 16 + hi * 8);

    f32x16 o_acc[2][2] = {};   // [dtile][ntile]
    float l_run[2] = {0.f, 0.f};  // per-ntile, own 16-key half

    // load tile 'it' into one named buffer set (8 x global_load_dwordx4)
    auto ldKV = [&](int it,
                    bf16x8& k0, bf16x8& k1, bf16x8& k2, bf16x8& k3,
                    bf16x8& v0, bf16x8& v1, bf16x8& v2, bf16x8& v3) {
        const __bf16* kp = Kl + it * (128 * HD);
        k0 = *(const bf16x8*)(kp);            // d 0..15 slice
        k1 = *(const bf16x8*)(kp + 16);       // d 16..31
        k2 = *(const bf16x8*)(kp + 32);       // d 32..47
        k3 = *(const bf16x8*)(kp + 48);       // d 48..63
        const __bf16* vp = Vl + it * 128;
        v0 = *(const bf16x8*)(vp);                  // dt0, keys 0..15
        v1 = *(const bf16x8*)(vp + 16);             // dt0, keys 16..31
        v2 = *(const bf16x8*)(vp + 32 * NPIX);      // dt1, keys 0..15
        v3 = *(const bf16x8*)(vp + 32 * NPIX + 16); // dt1, keys 16..31
    };

    // exp + row-sum + C32->B32 relayout for one ntile's S^T f32x16
    auto procP = [&](const f32x16& st, float& lrun, bf16x8& bc0, bf16x8& bc1) {
        float pf[16];
        #pragma unroll
        for (int r = 0; r < 16; ++r) pf[r] = EXP2(st[r]);
        lrun += (((pf[0] + pf[1]) + (pf[2] + pf[3])) + ((pf[4] + pf[5]) + (pf[6] + pf[7])))
              + (((pf[8] + pf[9]) + (pf[10] + pf[11])) + ((pf[12] + pf[13]) + (pf[14] + pf[15])));
        // chunk0 (keys 0..15): rows (r&3)+8*(r>>2)+4*hi for r=0..7
        unsigned x0 = pack_bf16x2(pf[0], pf[1]);   // keys (0,1)/(4,5)
        unsigned x1 = pack_bf16x2(pf[2], pf[3]);   // keys (2,3)/(6,7)
        unsigned x2 = pack_bf16x2(pf[4], pf[5]);   // keys (8,9)/(12,13)
        unsigned x3 = pack_bf16x2(pf[6], pf[7]);   // keys (10,11)/(14,15)
        asm("v_permlane32_swap_b32 %0, %1" : "+v"(x0), "+v"(x2));
        asm("v_permlane32_swap_b32 %0, %1" : "+v"(x1), "+v"(x3));
        uint32x4 w0; w0[0] = x0; w0[1] = x1; w0[2] = x2; w0[3] = x3;
        bc0 = __builtin_bit_cast(bf16x8, w0);      // B[k=key 0..15][n=q]
        // chunk1 (keys 16..31): r=8..15
        unsigned x4 = pack_bf16x2(pf[8], pf[9]);    // keys (16,17)/(20,21)
        unsigned x5 = pack_bf16x2(pf[10], pf[11]);  // keys (18,19)/(22,23)
        unsigned x6 = pack_bf16x2(pf[12], pf[13]);  // keys (24,25)/(28,29)
        unsigned x7 = pack_bf16x2(pf[14], pf[15]);  // keys (26,27)/(30,31)
        asm("v_permlane32_swap_b32 %0, %1" : "+v"(x4), "+v"(x6));
        asm("v_permlane32_swap_b32 %0, %1" : "+v"(x5), "+v"(x7));
        uint32x4 w1; w1[0] = x4; w1[1] = x5; w1[2] = x6; w1[3] = x7;
        bc1 = __builtin_bit_cast(bf16x8, w1);      // B[k=key 16..31][n=q]
    };

    auto step = [&](bf16x8 k0, bf16x8 k1, bf16x8 k2, bf16x8 k3,
                    bf16x8 v0, bf16x8 v1, bf16x8 v2, bf16x8 v3) {
        // S^T[key 32][q 64] = K Q^T: C col=q (c31), row=key
        f32x16 st0 = {}, st1 = {};
        st0 = __builtin_amdgcn_mfma_f32_32x32x16_bf16(k0, qf[0][0], st0, 0, 0, 0);
        st1 = __builtin_amdgcn_mfma_f32_32x32x16_bf16(k0, qf[1][0], st1, 0, 0, 0);
        st0 = __builtin_amdgcn_mfma_f32_32x32x16_bf16(k1, qf[0][1], st0, 0, 0, 0);
        st1 = __builtin_amdgcn_mfma_f32_32x32x16_bf16(k1, qf[1][1], st1, 0, 0, 0);
        st0 = __builtin_amdgcn_mfma_f32_32x32x16_bf16(k2, qf[0][2], st0, 0, 0, 0);
        st1 = __builtin_amdgcn_mfma_f32_32x32x16_bf16(k2, qf[1][2], st1, 0, 0, 0);
        st0 = __builtin_amdgcn_mfma_f32_32x32x16_bf16(k3, qf[0][3], st0, 0, 0, 0);
        st1 = __builtin_amdgcn_mfma_f32_32x32x16_bf16(k3, qf[1][3], st1, 0, 0, 0);

        bf16x8 b00, b01, b10, b11;           // [ntile][kchunk]
        procP(st0, l_run[0], b00, b01);
        procP(st1, l_run[1], b10, b11);

        // O^T[d][q] += V^T[d][key] P[key][q]
        o_acc[0][0] = __builtin_amdgcn_mfma_f32_32x32x16_bf16(v0, b00, o_acc[0][0], 0, 0, 0);
        o_acc[0][1] = __builtin_amdgcn_mfma_f32_32x32x16_bf16(v0, b10, o_acc[0][1], 0, 0, 0);
        o_acc[1][0] = __builtin_amdgcn_mfma_f32_32x32x16_bf16(v2, b00, o_acc[1][0], 0, 0, 0);
        o_acc[1][1] = __builtin_amdgcn_mfma_f32_32x32x16_bf16(v2, b10, o_acc[1][1], 0, 0, 0);
        o_acc[0][0] = __builtin_amdgcn_mfma_f32_32x32x16_bf16(v1, b01, o_acc[0][0], 0, 0, 0);
        o_acc[0][1] = __builtin_amdgcn_mfma_f32_32x32x16_bf16(v1, b11, o_acc[0][1], 0, 0, 0);
        o_acc[1][0] = __builtin_amdgcn_mfma_f32_32x32x16_bf16(v3, b01, o_acc[1][0], 0, 0, 0);
        o_acc[1][1] = __builtin_amdgcn_mfma_f32_32x32x16_bf16(v3, b11, o_acc[1][1], 0, 0, 0);
    };

    // R9-proven A/B register double-buffer
    bf16x8 ka0, ka1, ka2, ka3, va0, va1, va2, va3;
    bf16x8 kb0, kb1, kb2, kb3, vb0, vb1, vb2, vb3;
    ldKV(0, ka0, ka1, ka2, ka3, va0, va1, va2, va3);
    #pragma unroll 1
    for (int it = 0; it < 32; it += 2) {
        ldKV(it + 1, kb0, kb1, kb2, kb3, vb0, vb1, vb2, vb3);
        step(ka0, ka1, ka2, ka3, va0, va1, va2, va3);
        if (it + 2 < 32)
            ldKV(it + 2, ka0, ka1, ka2, ka3, va0, va1, va2, va3);
        step(kb0, kb1, kb2, kb3, vb0, vb1, vb2, vb3);
    }

    // ---- finalize l: combine own-half sums across hi via permlane32_swap ----
    {
        unsigned u0 = __builtin_bit_cast(unsigned, l_run[0]);
        unsigned u1 = __builtin_bit_cast(unsigned, l_run[1]);
        asm("v_permlane32_swap_b32 %0, %1" : "+v"(u0), "+v"(u1));
        // u0: lane<32 = half0(nt0,q=c31), lane>=32 = half0(nt1,q=c31)
        // u1: lane<32 = half1(nt0,q),     lane>=32 = half1(nt1,q)
        const float lfin = __builtin_bit_cast(float, u0) + __builtin_bit_cast(float, u1);
        cl[wave * 64 + hi * 32 + c31] = lfin;   // q-row = hi*32 + c31
    }

    // ---- o_acc -> co overlay [wave][q][d] (C32: d=(r&3)+8*(r>>2)+4*hi) ----
    #pragma unroll
    for (int dt = 0; dt < 2; ++dt)
        #pragma unroll
        for (int nt = 0; nt < 2; ++nt)
            #pragma unroll
            for (int g = 0; g < 4; ++g) {
                f32x4 v;
                v[0] = o_acc[dt][nt][g * 4 + 0];
                v[1] = o_acc[dt][nt][g * 4 + 1];
                v[2] = o_acc[dt][nt][g * 4 + 2];
                v[3] = o_acc[dt][nt][g * 4 + 3];
                *(f32x4*)(co + wave * 4352 + (nt * 32 + c31) * 68 + dt * 32 + g * 8 + hi * 4) = v;
            }
    __syncthreads();

    {
        const int row = t >> 2, dc = (t & 3) * 16;
        const float l = cl[row] + cl[64 + row] + cl[128 + row] + cl[192 + row];
        const float inv = 1.f / l;
        f32x4 s[4];
        #pragma unroll
        for (int j = 0; j < 4; ++j) {
            s[j] = f32x4{0.f, 0.f, 0.f, 0.f};
            #pragma unroll
            for (int w = 0; w < 4; ++w)
                s[j] += *(const f32x4*)(co + w * 4352 + row * 68 + dc + j * 4);
        }
        bf16x8 o1, o2;
        #pragma unroll
        for (int j = 0; j < 4; ++j) {
            o1[j]     = (__bf16)(s[0][j] * inv);
            o1[j + 4] = (__bf16)(s[1][j] * inv);
            o2[j]     = (__bf16)(s[2][j] * inv);
            o2[j + 4] = (__bf16)(s[3][j] * inv);
        }
        __bf16* dst = Sb + (p0 + row) * CCH + head * HD + dc;
        *(bf16x8*)(dst)     = o1;
        *(bf16x8*)(dst + 8) = o2;
    }
}

// ---------------------------------------------------------------------------
// K3: proj bf16 MFMA GEMM + bias + residual, fp32 out [c][pix].
// (unchanged from R12)
// ---------------------------------------------------------------------------
__global__ __launch_bounds__(256) void gemm_proj(
    const __bf16* __restrict__ Sb, const __bf16* __restrict__ Wpb,
    const float* __restrict__ bias, const float* __restrict__ X,
    float* __restrict__ Out)
{
    __shared__ __bf16 Bs[32 * XPITCH];

    const int t = threadIdx.x, lane = t & 63, wave = t >> 6;
    const int l16 = lane & 15, quad = lane >> 4;
    const int p0  = blockIdx.x * 32;
    const int och = blockIdx.y;

    #pragma unroll
    for (int pg = 0; pg < 4; ++pg) {
        bf16x8 v = *(const bf16x8*)(Sb + t * NPIX + p0 + pg * 8);
        #pragma unroll
        for (int j = 0; j < 8; ++j)
            Bs[(pg * 8 + j) * XPITCH + t] = v[j];
    }
    __syncthreads();

    const int pixset = wave & 1, ocset = wave >> 1;
    bf16x8 af[8];
    #pragma unroll
    for (int kc = 0; kc < 8; ++kc)
        af[kc] = *(const bf16x8*)(Bs + (pixset * 16 + l16) * XPITCH + kc * 32 + quad * 8);

    #pragma unroll
    for (int u = 0; u < 4; ++u) {
        f32x4 acc = {};
        const int oc_t = och * 128 + ocset * 64 + u * 16;
        #pragma unroll
        for (int kc = 0; kc < 8; ++kc) {
            bf16x8 wf = *(const bf16x8*)(Wpb + (oc_t + l16) * CCH + kc * 32 + quad * 8);
            acc = __builtin_amdgcn_mfma_f32_16x16x32_bf16(af[kc], wf, acc, 0, 0, 0);
        }
        const int oc  = oc_t + l16;
        const int pix = p0 + pixset * 16 + quad * 4;
        const float bz = bias[oc];
        f32x4 r4 = *(const f32x4*)(X + oc * NPIX + pix);
        f32x4 y;
        y[0] = acc[0] + bz + r4[0];
        y[1] = acc[1] + bz + r4[1];
        y[2] = acc[2] + bz + r4[2];
        y[3] = acc[3] + bz + r4[3];
        *(f32x4*)(Out + oc * NPIX + pix) = y;
    }
}

// ---------------------------------------------------------------------------
extern "C" void kernel_launch(void* const* d_in, const int* in_sizes, int n_in,
                              void* d_out, int out_size, void* d_ws, size_t ws_size,
                              hipStream_t stream)
{
    const float* x     = (const float*)d_in[0];
    const float* gamma = (const float*)d_in[1];
    const float* beta  = (const float*)d_in[2];
    const float* Wq    = (const float*)d_in[3];
    const float* bq    = (const float*)d_in[4];
    const float* Wk    = (const float*)d_in[5];
    const float* bk    = (const float*)d_in[6];
    const float* Wv    = (const float*)d_in[7];
    const float* bv    = (const float*)d_in[8];
    const float* Wp    = (const float*)d_in[9];
    const float* bp    = (const float*)d_in[10];
    float* out = (float*)d_out;

    char* ws = (char*)d_ws;
    float*  psum = (float*)(ws);                // 1KB stats partial sums
    float*  pssq = (float*)(ws + 1024);         // 1KB
    __bf16* Wb   = (__bf16*)(ws + 65536);       // 512KB bf16 4x[256][256]
    __bf16* Qb   = (__bf16*)(ws + (1 << 20));   // 2MB bf16 [head][pix][64]
    __bf16* Kb   = (__bf16*)(ws + (3 << 20));   // 2MB bf16 [head][pix][64]
    __bf16* Vb   = (__bf16*)(ws + (5 << 20));   // 2MB bf16 [c][pix]
    __bf16* Sb   = (__bf16*)(ws + (7 << 20));   // 2MB bf16 flat F

    stats_wconv<<<320, 256, 0, stream>>>(x, Wq, Wk, Wv, Wp, psum, pssq, Wb);

    dim3 gq(64, 6);
    gn_qkv<<<gq, 256, 0, stream>>>(x, gamma, beta, psum, pssq, Wb,
                                   bq, bk, bv, Qb, Kb, Vb);

    attn_mfma<<<256, 256, 0, stream>>>(Qb, Kb, Vb, Sb);

    dim3 gp(128, 2);
    gemm_proj<<<gp, 256, 0, stream>>>(Sb, Wb + 3 * 65536, bp, x, out);
}

// Round 8
// 141.647 us; speedup vs baseline: 1.0136x; 1.0088x over previous
//
#include <hip/hip_runtime.h>
#include <hip/hip_bf16.h>

// b=1, c=256, h=w=64 -> n=4096 pixels, 4 heads, hd=64, 32 groups x 8 ch.
// scale = hd^-0.5 * log2(e) = 0.18033688, folded into Wq (K0) and bq (K1
// epilogue) so attention softmax uses native v_exp_f32 (exp2) directly.
#define NPIX 4096
#define CCH  256
#define HD   64
#define GSIZE 32768   // 8 ch * 4096 pix per group

#define QSCALE 0.18033688f   // 0.125 * log2(e); softmax in base-2 domain

typedef __bf16 bf16x8 __attribute__((ext_vector_type(8)));
typedef __bf16 bf16x4 __attribute__((ext_vector_type(4)));
typedef __bf16 bf16x2 __attribute__((ext_vector_type(2)));
typedef float  f32x4  __attribute__((ext_vector_type(4)));
typedef unsigned int uint32x4 __attribute__((ext_vector_type(4)));

#define XPITCH 264   // X/F panel pitch (bf16) for K1/K3

#if __has_builtin(__builtin_amdgcn_exp2f)
#define EXP2(x) __builtin_amdgcn_exp2f(x)
#else
#define EXP2(x) __expf((x) * 0.6931471805599453f)
#endif

// MFMA 16x16x32_bf16 layouts (verified m89/m91):
//   A[m=lane&15][k=quad*8+j]; B[k=quad*8+j][n=lane&15]; C: row=quad*4+reg, col=lane&15

__device__ __forceinline__ unsigned pack_bf16x2(float lo, float hi)
{
    bf16x2 v;
    v[0] = (__bf16)lo;
    v[1] = (__bf16)hi;
    return __builtin_bit_cast(unsigned, v);
}

// ---------------------------------------------------------------------------
// K0: blocks 0..255: per-(group,1/8th) partial sums -> psum/pssq[256].
//     blocks 256..319: weight fp32->bf16 convert (Wq scaled by QSCALE).
// ---------------------------------------------------------------------------
__global__ __launch_bounds__(256) void stats_wconv(
    const float* __restrict__ X,
    const float* __restrict__ Wq, const float* __restrict__ Wk,
    const float* __restrict__ Wv, const float* __restrict__ Wp,
    float* __restrict__ psum, float* __restrict__ pssq, __bf16* __restrict__ Wb)
{
    const int bid = blockIdx.x, t = threadIdx.x;
    if (bid < 256) {
        const float* base = X + bid * 4096;   // (g = bid>>3, seg = bid&7)
        float sum = 0.f, ssq = 0.f;
        #pragma unroll
        for (int k = 0; k < 4; ++k) {
            float4 v = *(const float4*)(base + t * 4 + k * 1024);
            sum += v.x + v.y + v.z + v.w;
            ssq += v.x * v.x + v.y * v.y + v.z * v.z + v.w * v.w;
        }
        #pragma unroll
        for (int off = 1; off < 64; off <<= 1) {
            sum += __shfl_xor(sum, off);
            ssq += __shfl_xor(ssq, off);
        }
        __shared__ float red[2][4];
        const int wv = t >> 6;
        if ((t & 63) == 0) { red[0][wv] = sum; red[1][wv] = ssq; }
        __syncthreads();
        if (t == 0) {
            psum[bid] = red[0][0] + red[0][1] + red[0][2] + red[0][3];
            pssq[bid] = red[1][0] + red[1][1] + red[1][2] + red[1][3];
        }
    } else {
        const int j0 = (bid - 256) * 4096 + t * 16;
        const int m  = j0 >> 16;
        const float* W = (m == 0) ? Wq : (m == 1) ? Wk : (m == 2) ? Wv : Wp;
        const float sc = (m == 0) ? QSCALE : 1.f;
        const int off = j0 & 65535;
        #pragma unroll
        for (int k = 0; k < 4; ++k) {
            float4 v = *(const float4*)(W + off + k * 4);
            bf16x4 o;
            o[0] = (__bf16)(v.x * sc); o[1] = (__bf16)(v.y * sc);
            o[2] = (__bf16)(v.z * sc); o[3] = (__bf16)(v.w * sc);
            *(bf16x4*)(Wb + m * 65536 + off + k * 4) = o;
        }
    }
}

// ---------------------------------------------------------------------------
// K1: fused GroupNorm-apply + QKV MFMA GEMM. grid (64 pixblk, 6: z*2+och).
// (unchanged; qs = QSCALE)
// ---------------------------------------------------------------------------
__global__ __launch_bounds__(256) void gn_qkv(
    const float* __restrict__ X, const float* __restrict__ gamma,
    const float* __restrict__ beta,
    const float* __restrict__ psum, const float* __restrict__ pssq,
    const __bf16* __restrict__ Wb,
    const float* __restrict__ bq, const float* __restrict__ bk,
    const float* __restrict__ bv,
    __bf16* __restrict__ Qb, __bf16* __restrict__ Kb, __bf16* __restrict__ Vb)
{
    __shared__ __bf16 tile[64 * XPITCH];
    __shared__ float al[256], bl[256];

    const int t = threadIdx.x, lane = t & 63, wave = t >> 6;
    const int l16 = lane & 15, quad = lane >> 4;
    const int p0 = blockIdx.x * 64;
    const int z = blockIdx.y >> 1, och = blockIdx.y & 1;

    {
        const int g = t >> 3;
        float s = 0.f, q = 0.f;
        #pragma unroll
        for (int j = 0; j < 8; ++j) { s += psum[g * 8 + j]; q += pssq[g * 8 + j]; }
        const float mu  = s * (1.f / GSIZE);
        const float var = q * (1.f / GSIZE) - mu * mu;
        const float a = gamma[t] * rsqrtf(var + 1e-6f);
        al[t] = a;
        bl[t] = beta[t] - mu * a;
    }
    __syncthreads();

    #pragma unroll 4
    for (int i = 0; i < 16; ++i) {
        const int c4 = wave * 64 + i * 4;
        f32x4 a4 = *(const f32x4*)(al + c4);
        f32x4 b4 = *(const f32x4*)(bl + c4);
        bf16x4 pk;
        pk[0] = (__bf16)(X[(c4 + 0) * NPIX + p0 + lane] * a4[0] + b4[0]);
        pk[1] = (__bf16)(X[(c4 + 1) * NPIX + p0 + lane] * a4[1] + b4[1]);
        pk[2] = (__bf16)(X[(c4 + 2) * NPIX + p0 + lane] * a4[2] + b4[2]);
        pk[3] = (__bf16)(X[(c4 + 3) * NPIX + p0 + lane] * a4[3] + b4[3]);
        *(bf16x4*)(tile + lane * XPITCH + c4) = pk;
    }
    __syncthreads();

    const int pw = wave * 16;
    bf16x8 xf[8];
    #pragma unroll
    for (int kc = 0; kc < 8; ++kc)
        xf[kc] = *(const bf16x8*)(tile + (pw + l16) * XPITCH + kc * 32 + quad * 8);

    const __bf16* Wz = Wb + z * 65536;
    const float* bias = (z == 0) ? bq : (z == 1) ? bk : bv;

    if (z < 2) {
        const float qs = (z == 0) ? QSCALE : 1.f;
        __bf16* dst = (z == 0) ? Qb : Kb;
        #pragma unroll
        for (int grp = 0; grp < 2; ++grp) {
            f32x4 acc[4] = {};
            #pragma unroll
            for (int kc = 0; kc < 8; ++kc) {
                #pragma unroll
                for (int u = 0; u < 4; ++u) {
                    bf16x8 wf = *(const bf16x8*)(Wz + (och * 128 + (grp * 4 + u) * 16 + l16) * CCH + kc * 32 + quad * 8);
                    acc[u] = __builtin_amdgcn_mfma_f32_16x16x32_bf16(wf, xf[kc], acc[u], 0, 0, 0);
                }
            }
            #pragma unroll
            for (int u = 0; u < 4; ++u) {
                const int ot = och * 8 + grp * 4 + u;
                f32x4 bz = *(const f32x4*)(bias + och * 128 + (grp * 4 + u) * 16 + quad * 4);
                bf16x4 o;
                o[0] = (__bf16)(acc[u][0] + bz[0] * qs);
                o[1] = (__bf16)(acc[u][1] + bz[1] * qs);
                o[2] = (__bf16)(acc[u][2] + bz[2] * qs);
                o[3] = (__bf16)(acc[u][3] + bz[3] * qs);
                const int head = ot >> 2, dloc = (ot & 3) * 16 + quad * 4;
                *(bf16x4*)(dst + head * (NPIX * HD) + (p0 + pw + l16) * HD + dloc) = o;
            }
        }
    } else {
        #pragma unroll
        for (int grp = 0; grp < 2; ++grp) {
            f32x4 acc[4] = {};
            #pragma unroll
            for (int kc = 0; kc < 8; ++kc) {
                #pragma unroll
                for (int u = 0; u < 4; ++u) {
                    bf16x8 wf = *(const bf16x8*)(Wz + (och * 128 + (grp * 4 + u) * 16 + l16) * CCH + kc * 32 + quad * 8);
                    acc[u] = __builtin_amdgcn_mfma_f32_16x16x32_bf16(xf[kc], wf, acc[u], 0, 0, 0);
                }
            }
            #pragma unroll
            for (int u = 0; u < 4; ++u) {
                const int oc = och * 128 + (grp * 4 + u) * 16 + l16;
                const float bz = bias[oc];
                bf16x4 o;
                o[0] = (__bf16)(acc[u][0] + bz); o[1] = (__bf16)(acc[u][1] + bz);
                o[2] = (__bf16)(acc[u][2] + bz); o[3] = (__bf16)(acc[u][3] + bz);
                *(bf16x4*)(Vb + oc * NPIX + p0 + pw + quad * 4) = o;
            }
        }
    }
}

// ---------------------------------------------------------------------------
// K2 (R16): revert to the session-best R12 zero-LDS 16x16 kernel, with one
// free reordering: each tile's 8 loads split into K-cluster (before QK(t))
// and V-cluster (after QK(t)) — V gets an extra phase of latency cover and
// any conservative waitcnt drains fewer outstanding loads. No added
// instructions vs R12 (the R14/R15 regressions added work; this does not).
// R15 post-mortem: halving instruction count at same pipe-cycles nulled ->
// per-tile time is scheduler/latency-residual-bound; banking best-known.
// ---------------------------------------------------------------------------
__global__ __launch_bounds__(256, 1) void attn_mfma(
    const __bf16* __restrict__ Qb, const __bf16* __restrict__ Kb,
    const __bf16* __restrict__ Vb, __bf16* __restrict__ Sb)
{
    __shared__ __align__(16) float co[4 * 64 * 68];  // 69632 B merge buffer
    __shared__ float cl[4 * 64];

    const int t = threadIdx.x, lane = t & 63, wave = t >> 6;
    const int l16 = lane & 15, quad = lane >> 4;

    const int bid  = blockIdx.x;
    const int head = (bid & 7) >> 1;                   // XCD-pair pinning
    const int qt   = ((bid >> 3) << 1) | (bid & 1);    // 0..63
    const int p0   = qt * 64;

    const __bf16* Qh = Qb + head * (NPIX * HD);
    const __bf16* Kh = Kb + head * (NPIX * HD) + (wave * 32 + l16) * HD + quad * 8;
    const __bf16* Vh = Vb + head * (HD * NPIX) + l16 * NPIX + wave * 32 + quad * 8;

    // Q B-frags for 64 shared rows: B[k=d][n=row16]
    bf16x8 qf[4][2];
    #pragma unroll
    for (int rt = 0; rt < 4; ++rt) {
        const __bf16* qp = Qh + (p0 + rt * 16 + l16) * HD + quad * 8;
        qf[rt][0] = *(const bf16x8*)(qp);
        qf[rt][1] = *(const bf16x8*)(qp + 32);
    }

    bf16x8 ones;
    #pragma unroll
    for (int j = 0; j < 8; ++j) ones[j] = (__bf16)1.0f;

    f32x4 l_acc[4] = {};
    f32x4 o_acc[4][4] = {};   // [dt][rt]

    auto ldK = [&](int it, bf16x8& k0, bf16x8& k1, bf16x8& k2, bf16x8& k3) {
        const __bf16* kp = Kh + it * (128 * HD);
        k0 = *(const bf16x8*)(kp);
        k1 = *(const bf16x8*)(kp + 32);
        k2 = *(const bf16x8*)(kp + 16 * HD);
        k3 = *(const bf16x8*)(kp + 16 * HD + 32);
    };
    auto ldV = [&](int it, bf16x8& v0, bf16x8& v1, bf16x8& v2, bf16x8& v3) {
        const __bf16* vp = Vh + it * 128;
        v0 = *(const bf16x8*)(vp);
        v1 = *(const bf16x8*)(vp + 16 * NPIX);
        v2 = *(const bf16x8*)(vp + 32 * NPIX);
        v3 = *(const bf16x8*)(vp + 48 * NPIX);
    };

    // S^T = K Q^T : C(key_local = kt*16+quad*4+r, row = rt*16+l16)
    auto qk = [&](bf16x8 k0, bf16x8 k1, bf16x8 k2, bf16x8 k3,
                  f32x4 (&s0)[4], f32x4 (&s1)[4]) {
        #pragma unroll
        for (int rt = 0; rt < 4; ++rt) {
            s0[rt] = f32x4{0.f, 0.f, 0.f, 0.f};
            s1[rt] = f32x4{0.f, 0.f, 0.f, 0.f};
            s0[rt] = __builtin_amdgcn_mfma_f32_16x16x32_bf16(k0, qf[rt][0], s0[rt], 0, 0, 0);
            s0[rt] = __builtin_amdgcn_mfma_f32_16x16x32_bf16(k1, qf[rt][1], s0[rt], 0, 0, 0);
            s1[rt] = __builtin_amdgcn_mfma_f32_16x16x32_bf16(k2, qf[rt][0], s1[rt], 0, 0, 0);
            s1[rt] = __builtin_amdgcn_mfma_f32_16x16x32_bf16(k3, qf[rt][1], s1[rt], 0, 0, 0);
        }
    };

    // P = exp2(S'), C->B relayout in-register, l += rowsum, O += V^T P^T
    auto pvx = [&](const f32x4 (&s0)[4], const f32x4 (&s1)[4],
                   bf16x8 v0, bf16x8 v1, bf16x8 v2, bf16x8 v3) {
        #pragma unroll
        for (int rt = 0; rt < 4; ++rt) {
            unsigned a0 = pack_bf16x2(EXP2(s0[rt][0]), EXP2(s0[rt][1]));
            unsigned a1 = pack_bf16x2(EXP2(s0[rt][2]), EXP2(s0[rt][3]));
            unsigned b0 = pack_bf16x2(EXP2(s1[rt][0]), EXP2(s1[rt][1]));
            unsigned b1 = pack_bf16x2(EXP2(s1[rt][2]), EXP2(s1[rt][3]));
            // swap32 then swap16: (a0,b0) -> (w0,w2); (a1,b1) -> (w1,w3)
            asm("v_permlane32_swap_b32 %0, %1" : "+v"(a0), "+v"(b0));
            asm("v_permlane32_swap_b32 %0, %1" : "+v"(a1), "+v"(b1));
            asm("v_permlane16_swap_b32 %0, %1" : "+v"(a0), "+v"(b0));
            asm("v_permlane16_swap_b32 %0, %1" : "+v"(a1), "+v"(b1));
            uint32x4 w;
            w[0] = a0; w[1] = a1; w[2] = b0; w[3] = b1;
            const bf16x8 bp = __builtin_bit_cast(bf16x8, w);  // B[k=key32][n=row]
            l_acc[rt] = __builtin_amdgcn_mfma_f32_16x16x32_bf16(ones, bp, l_acc[rt], 0, 0, 0);
            o_acc[0][rt] = __builtin_amdgcn_mfma_f32_16x16x32_bf16(v0, bp, o_acc[0][rt], 0, 0, 0);
            o_acc[1][rt] = __builtin_amdgcn_mfma_f32_16x16x32_bf16(v1, bp, o_acc[1][rt], 0, 0, 0);
            o_acc[2][rt] = __builtin_amdgcn_mfma_f32_16x16x32_bf16(v2, bp, o_acc[2][rt], 0, 0, 0);
            o_acc[3][rt] = __builtin_amdgcn_mfma_f32_16x16x32_bf16(v3, bp, o_acc[3][rt], 0, 0, 0);
        }
    };

    // named A/B tile contexts, 1-deep double-buffer, K/V load clusters split
    bf16x8 kA0, kA1, kA2, kA3, vA0, vA1, vA2, vA3;
    bf16x8 kB0, kB1, kB2, kB3, vB0, vB1, vB2, vB3;
    f32x4 sA0[4], sA1[4], sB0[4], sB1[4];

    ldK(0, kA0, kA1, kA2, kA3);
    ldV(0, vA0, vA1, vA2, vA3);

    #pragma unroll 1
    for (int it = 0; it < 32; it += 2) {
        ldK(it + 1, kB0, kB1, kB2, kB3);
        qk(kA0, kA1, kA2, kA3, sA0, sA1);
        ldV(it + 1, vB0, vB1, vB2, vB3);
        pvx(sA0, sA1, vA0, vA1, vA2, vA3);
        if (it + 2 < 32) ldK(it + 2, kA0, kA1, kA2, kA3);
        qk(kB0, kB1, kB2, kB3, sB0, sB1);
        if (it + 2 < 32) ldV(it + 2, vA0, vA1, vA2, vA3);
        pvx(sB0, sB1, vB0, vB1, vB2, vB3);
    }

    // ---- in-LDS 4-way key merge ----
    #pragma unroll
    for (int dt = 0; dt < 4; ++dt)
        #pragma unroll
        for (int rt = 0; rt < 4; ++rt)
            *(f32x4*)(co + wave * 4352 + (rt * 16 + l16) * 68 + dt * 16 + quad * 4) = o_acc[dt][rt];
    if (quad == 0) {
        #pragma unroll
        for (int rt = 0; rt < 4; ++rt)
            cl[wave * 64 + rt * 16 + l16] = l_acc[rt][0];
    }
    __syncthreads();

    {
        const int row = t >> 2, dc = (t & 3) * 16;
        const float l = cl[row] + cl[64 + row] + cl[128 + row] + cl[192 + row];
        const float inv = 1.f / l;
        f32x4 s[4];
        #pragma unroll
        for (int j = 0; j < 4; ++j) {
            s[j] = f32x4{0.f, 0.f, 0.f, 0.f};
            #pragma unroll
            for (int w = 0; w < 4; ++w)
                s[j] += *(const f32x4*)(co + w * 4352 + row * 68 + dc + j * 4);
        }
        bf16x8 o1, o2;
        #pragma unroll
        for (int j = 0; j < 4; ++j) {
            o1[j]     = (__bf16)(s[0][j] * inv);
            o1[j + 4] = (__bf16)(s[1][j] * inv);
            o2[j]     = (__bf16)(s[2][j] * inv);
            o2[j + 4] = (__bf16)(s[3][j] * inv);
        }
        __bf16* dst = Sb + (p0 + row) * CCH + head * HD + dc;
        *(bf16x8*)(dst)     = o1;
        *(bf16x8*)(dst + 8) = o2;
    }
}

// ---------------------------------------------------------------------------
// K3: proj bf16 MFMA GEMM + bias + residual, fp32 out [c][pix].
// (unchanged from R12)
// ---------------------------------------------------------------------------
__global__ __launch_bounds__(256) void gemm_proj(
    const __bf16* __restrict__ Sb, const __bf16* __restrict__ Wpb,
    const float* __restrict__ bias, const float* __restrict__ X,
    float* __restrict__ Out)
{
    __shared__ __bf16 Bs[32 * XPITCH];

    const int t = threadIdx.x, lane = t & 63, wave = t >> 6;
    const int l16 = lane & 15, quad = lane >> 4;
    const int p0  = blockIdx.x * 32;
    const int och = blockIdx.y;

    #pragma unroll
    for (int pg = 0; pg < 4; ++pg) {
        bf16x8 v = *(const bf16x8*)(Sb + t * NPIX + p0 + pg * 8);
        #pragma unroll
        for (int j = 0; j < 8; ++j)
            Bs[(pg * 8 + j) * XPITCH + t] = v[j];
    }
    __syncthreads();

    const int pixset = wave & 1, ocset = wave >> 1;
    bf16x8 af[8];
    #pragma unroll
    for (int kc = 0; kc < 8; ++kc)
        af[kc] = *(const bf16x8*)(Bs + (pixset * 16 + l16) * XPITCH + kc * 32 + quad * 8);

    #pragma unroll
    for (int u = 0; u < 4; ++u) {
        f32x4 acc = {};
        const int oc_t = och * 128 + ocset * 64 + u * 16;
        #pragma unroll
        for (int kc = 0; kc < 8; ++kc) {
            bf16x8 wf = *(const bf16x8*)(Wpb + (oc_t + l16) * CCH + kc * 32 + quad * 8);
            acc = __builtin_amdgcn_mfma_f32_16x16x32_bf16(af[kc], wf, acc, 0, 0, 0);
        }
        const int oc  = oc_t + l16;
        const int pix = p0 + pixset * 16 + quad * 4;
        const float bz = bias[oc];
        f32x4 r4 = *(const f32x4*)(X + oc * NPIX + pix);
        f32x4 y;
        y[0] = acc[0] + bz + r4[0];
        y[1] = acc[1] + bz + r4[1];
        y[2] = acc[2] + bz + r4[2];
        y[3] = acc[3] + bz + r4[3];
        *(f32x4*)(Out + oc * NPIX + pix) = y;
    }
}

// ---------------------------------------------------------------------------
extern "C" void kernel_launch(void* const* d_in, const int* in_sizes, int n_in,
                              void* d_out, int out_size, void* d_ws, size_t ws_size,
                              hipStream_t stream)
{
    const float* x     = (const float*)d_in[0];
    const float* gamma = (const float*)d_in[1];
    const float* beta  = (const float*)d_in[2];
    const float* Wq    = (const float*)d_in[3];
    const float* bq    = (const float*)d_in[4];
    const float* Wk    = (const float*)d_in[5];
    const float* bk    = (const float*)d_in[6];
    const float* Wv    = (const float*)d_in[7];
    const float* bv    = (const float*)d_in[8];
    const float* Wp    = (const float*)d_in[9];
    const float* bp    = (const float*)d_in[10];
    float* out = (float*)d_out;

    char* ws = (char*)d_ws;
    float*  psum = (float*)(ws);                // 1KB stats partial sums
    float*  pssq = (float*)(ws + 1024);         // 1KB
    __bf16* Wb   = (__bf16*)(ws + 65536);       // 512KB bf16 4x[256][256]
    __bf16* Qb   = (__bf16*)(ws + (1 << 20));   // 2MB bf16 [head][pix][64]
    __bf16* Kb   = (__bf16*)(ws + (3 << 20));   // 2MB bf16 [head][pix][64]
    __bf16* Vb   = (__bf16*)(ws + (5 << 20));   // 2MB bf16 [c][pix]
    __bf16* Sb   = (__bf16*)(ws + (7 << 20));   // 2MB bf16 flat F

    stats_wconv<<<320, 256, 0, stream>>>(x, Wq, Wk, Wv, Wp, psum, pssq, Wb);

    dim3 gq(64, 6);
    gn_qkv<<<gq, 256, 0, stream>>>(x, gamma, beta, psum, pssq, Wb,
                                   bq, bk, bv, Qb, Kb, Vb);

    attn_mfma<<<256, 256, 0, stream>>>(Qb, Kb, Vb, Sb);

    dim3 gp(128, 2);
    gemm_proj<<<gp, 256, 0, stream>>>(Sb, Wb + 3 * 65536, bp, x, out);
}

// Round 9
// 135.792 us; speedup vs baseline: 1.0573x; 1.0431x over previous
//
#include <hip/hip_runtime.h>
#include <hip/hip_bf16.h>

// b=1, c=256, h=w=64 -> n=4096 pixels, 4 heads, hd=64, 32 groups x 8 ch.
// scale = hd^-0.5 * log2(e) = 0.18033688, folded into Wq (K0) and bq (K1
// epilogue) so attention softmax uses native v_exp_f32 (exp2) directly.
#define NPIX 4096
#define CCH  256
#define HD   64
#define GSIZE 32768   // 8 ch * 4096 pix per group

#define QSCALE 0.18033688f   // 0.125 * log2(e); softmax in base-2 domain

typedef __bf16 bf16x8 __attribute__((ext_vector_type(8)));
typedef __bf16 bf16x4 __attribute__((ext_vector_type(4)));
typedef __bf16 bf16x2 __attribute__((ext_vector_type(2)));
typedef float  f32x4  __attribute__((ext_vector_type(4)));
typedef unsigned int uint32x4 __attribute__((ext_vector_type(4)));

#define XPITCH 264   // X/F panel pitch (bf16) for K1/K3

#if __has_builtin(__builtin_amdgcn_exp2f)
#define EXP2(x) __builtin_amdgcn_exp2f(x)
#else
#define EXP2(x) __expf((x) * 0.6931471805599453f)
#endif

// MFMA 16x16x32_bf16 layouts (verified m89/m91):
//   A[m=lane&15][k=quad*8+j]; B[k=quad*8+j][n=lane&15]; C: row=quad*4+reg, col=lane&15

__device__ __forceinline__ unsigned pack_bf16x2(float lo, float hi)
{
    bf16x2 v;
    v[0] = (__bf16)lo;
    v[1] = (__bf16)hi;
    return __builtin_bit_cast(unsigned, v);
}

// direct global->LDS DMA, 16B per lane; LDS dest = wave-uniform base + lane*16
__device__ __forceinline__ void gload_lds16(const void* g, void* l)
{
    __builtin_amdgcn_global_load_lds(
        (const __attribute__((address_space(1))) void*)g,
        (__attribute__((address_space(3))) void*)l, 16, 0, 0);
}

// ---------------------------------------------------------------------------
// K0: blocks 0..255: per-(group,1/8th) partial sums -> psum/pssq[256].
//     blocks 256..319: weight fp32->bf16 convert (Wq scaled by QSCALE).
// ---------------------------------------------------------------------------
__global__ __launch_bounds__(256) void stats_wconv(
    const float* __restrict__ X,
    const float* __restrict__ Wq, const float* __restrict__ Wk,
    const float* __restrict__ Wv, const float* __restrict__ Wp,
    float* __restrict__ psum, float* __restrict__ pssq, __bf16* __restrict__ Wb)
{
    const int bid = blockIdx.x, t = threadIdx.x;
    if (bid < 256) {
        const float* base = X + bid * 4096;   // (g = bid>>3, seg = bid&7)
        float sum = 0.f, ssq = 0.f;
        #pragma unroll
        for (int k = 0; k < 4; ++k) {
            float4 v = *(const float4*)(base + t * 4 + k * 1024);
            sum += v.x + v.y + v.z + v.w;
            ssq += v.x * v.x + v.y * v.y + v.z * v.z + v.w * v.w;
        }
        #pragma unroll
        for (int off = 1; off < 64; off <<= 1) {
            sum += __shfl_xor(sum, off);
            ssq += __shfl_xor(ssq, off);
        }
        __shared__ float red[2][4];
        const int wv = t >> 6;
        if ((t & 63) == 0) { red[0][wv] = sum; red[1][wv] = ssq; }
        __syncthreads();
        if (t == 0) {
            psum[bid] = red[0][0] + red[0][1] + red[0][2] + red[0][3];
            pssq[bid] = red[1][0] + red[1][1] + red[1][2] + red[1][3];
        }
    } else {
        const int j0 = (bid - 256) * 4096 + t * 16;
        const int m  = j0 >> 16;
        const float* W = (m == 0) ? Wq : (m == 1) ? Wk : (m == 2) ? Wv : Wp;
        const float sc = (m == 0) ? QSCALE : 1.f;
        const int off = j0 & 65535;
        #pragma unroll
        for (int k = 0; k < 4; ++k) {
            float4 v = *(const float4*)(W + off + k * 4);
            bf16x4 o;
            o[0] = (__bf16)(v.x * sc); o[1] = (__bf16)(v.y * sc);
            o[2] = (__bf16)(v.z * sc); o[3] = (__bf16)(v.w * sc);
            *(bf16x4*)(Wb + m * 65536 + off + k * 4) = o;
        }
    }
}

// ---------------------------------------------------------------------------
// K1: fused GroupNorm-apply + QKV MFMA GEMM. grid (64 pixblk, 6: z*2+och).
// (unchanged; qs = QSCALE)
// ---------------------------------------------------------------------------
__global__ __launch_bounds__(256) void gn_qkv(
    const float* __restrict__ X, const float* __restrict__ gamma,
    const float* __restrict__ beta,
    const float* __restrict__ psum, const float* __restrict__ pssq,
    const __bf16* __restrict__ Wb,
    const float* __restrict__ bq, const float* __restrict__ bk,
    const float* __restrict__ bv,
    __bf16* __restrict__ Qb, __bf16* __restrict__ Kb, __bf16* __restrict__ Vb)
{
    __shared__ __bf16 tile[64 * XPITCH];
    __shared__ float al[256], bl[256];

    const int t = threadIdx.x, lane = t & 63, wave = t >> 6;
    const int l16 = lane & 15, quad = lane >> 4;
    const int p0 = blockIdx.x * 64;
    const int z = blockIdx.y >> 1, och = blockIdx.y & 1;

    {
        const int g = t >> 3;
        float s = 0.f, q = 0.f;
        #pragma unroll
        for (int j = 0; j < 8; ++j) { s += psum[g * 8 + j]; q += pssq[g * 8 + j]; }
        const float mu  = s * (1.f / GSIZE);
        const float var = q * (1.f / GSIZE) - mu * mu;
        const float a = gamma[t] * rsqrtf(var + 1e-6f);
        al[t] = a;
        bl[t] = beta[t] - mu * a;
    }
    __syncthreads();

    #pragma unroll 4
    for (int i = 0; i < 16; ++i) {
        const int c4 = wave * 64 + i * 4;
        f32x4 a4 = *(const f32x4*)(al + c4);
        f32x4 b4 = *(const f32x4*)(bl + c4);
        bf16x4 pk;
        pk[0] = (__bf16)(X[(c4 + 0) * NPIX + p0 + lane] * a4[0] + b4[0]);
        pk[1] = (__bf16)(X[(c4 + 1) * NPIX + p0 + lane] * a4[1] + b4[1]);
        pk[2] = (__bf16)(X[(c4 + 2) * NPIX + p0 + lane] * a4[2] + b4[2]);
        pk[3] = (__bf16)(X[(c4 + 3) * NPIX + p0 + lane] * a4[3] + b4[3]);
        *(bf16x4*)(tile + lane * XPITCH + c4) = pk;
    }
    __syncthreads();

    const int pw = wave * 16;
    bf16x8 xf[8];
    #pragma unroll
    for (int kc = 0; kc < 8; ++kc)
        xf[kc] = *(const bf16x8*)(tile + (pw + l16) * XPITCH + kc * 32 + quad * 8);

    const __bf16* Wz = Wb + z * 65536;
    const float* bias = (z == 0) ? bq : (z == 1) ? bk : bv;

    if (z < 2) {
        const float qs = (z == 0) ? QSCALE : 1.f;
        __bf16* dst = (z == 0) ? Qb : Kb;
        #pragma unroll
        for (int grp = 0; grp < 2; ++grp) {
            f32x4 acc[4] = {};
            #pragma unroll
            for (int kc = 0; kc < 8; ++kc) {
                #pragma unroll
                for (int u = 0; u < 4; ++u) {
                    bf16x8 wf = *(const bf16x8*)(Wz + (och * 128 + (grp * 4 + u) * 16 + l16) * CCH + kc * 32 + quad * 8);
                    acc[u] = __builtin_amdgcn_mfma_f32_16x16x32_bf16(wf, xf[kc], acc[u], 0, 0, 0);
                }
            }
            #pragma unroll
            for (int u = 0; u < 4; ++u) {
                const int ot = och * 8 + grp * 4 + u;
                f32x4 bz = *(const f32x4*)(bias + och * 128 + (grp * 4 + u) * 16 + quad * 4);
                bf16x4 o;
                o[0] = (__bf16)(acc[u][0] + bz[0] * qs);
                o[1] = (__bf16)(acc[u][1] + bz[1] * qs);
                o[2] = (__bf16)(acc[u][2] + bz[2] * qs);
                o[3] = (__bf16)(acc[u][3] + bz[3] * qs);
                const int head = ot >> 2, dloc = (ot & 3) * 16 + quad * 4;
                *(bf16x4*)(dst + head * (NPIX * HD) + (p0 + pw + l16) * HD + dloc) = o;
            }
        }
    } else {
        #pragma unroll
        for (int grp = 0; grp < 2; ++grp) {
            f32x4 acc[4] = {};
            #pragma unroll
            for (int kc = 0; kc < 8; ++kc) {
                #pragma unroll
                for (int u = 0; u < 4; ++u) {
                    bf16x8 wf = *(const bf16x8*)(Wz + (och * 128 + (grp * 4 + u) * 16 + l16) * CCH + kc * 32 + quad * 8);
                    acc[u] = __builtin_amdgcn_mfma_f32_16x16x32_bf16(xf[kc], wf, acc[u], 0, 0, 0);
                }
            }
            #pragma unroll
            for (int u = 0; u < 4; ++u) {
                const int oc = och * 128 + (grp * 4 + u) * 16 + l16;
                const float bz = bias[oc];
                bf16x4 o;
                o[0] = (__bf16)(acc[u][0] + bz); o[1] = (__bf16)(acc[u][1] + bz);
                o[2] = (__bf16)(acc[u][2] + bz); o[3] = (__bf16)(acc[u][3] + bz);
                *(bf16x4*)(Vb + oc * NPIX + p0 + pw + quad * 4) = o;
            }
        }
    }
}

// ---------------------------------------------------------------------------
// K2 (R17): allocator-proof pipelined attention via global_load_lds DMA.
// Post-mortem of R9-R16: every register-staged variant showed VGPR_Count far
// below live-buffer requirements -> the allocator dissolved every intended
// prefetch; all "nulls" measured allocator-rescheduled code. global_load_lds
// has no VGPR destination, so issue distance is enforced by counted
// s_waitcnt vmcnt(8) (never 0 in-loop, AITER pattern) + raw s_barrier; the
// compiler cannot sink it. ds_read bank conflicts (row-major 128B rows =
// 16-way) killed by both-sides XOR swizzle (T2/rule 21): LDS linear, global
// SOURCE col pre-swizzled with col ^= (row&7)<<4, reads apply the same
// involution -> 2-way (free). Compute core + epilogue byte-identical to the
// green R12 kernel. LDS: 2 x (16K K + 16K V) = 64K, merge overlay after loop.
// ---------------------------------------------------------------------------
#define OFFK0 0
#define OFFK1 16384
#define OFFV0 32768
#define OFFV1 49152
#define SMEMSZ 70656   // max(64K buffers, 69632 co + 1024 cl) via overlay

__global__ __launch_bounds__(256, 1) void attn_mfma(
    const __bf16* __restrict__ Qb, const __bf16* __restrict__ Kb,
    const __bf16* __restrict__ Vb, __bf16* __restrict__ Sb)
{
    __shared__ __align__(16) char smem[SMEMSZ];

    const int t = threadIdx.x, lane = t & 63, wave = t >> 6;
    const int l16 = lane & 15, quad = lane >> 4;

    const int bid  = blockIdx.x;
    const int head = (bid & 7) >> 1;                   // XCD-pair pinning
    const int qt   = ((bid >> 3) << 1) | (bid & 1);    // 0..63
    const int p0   = qt * 64;

    const __bf16* Qh = Qb + head * (NPIX * HD);

    // Q B-frags for 64 shared rows: B[k=d][n=row16]
    bf16x8 qf[4][2];
    #pragma unroll
    for (int rt = 0; rt < 4; ++rt) {
        const __bf16* qp = Qh + (p0 + rt * 16 + l16) * HD + quad * 8;
        qf[rt][0] = *(const bf16x8*)(qp);
        qf[rt][1] = *(const bf16x8*)(qp + 32);
    }

    bf16x8 ones;
    #pragma unroll
    for (int j = 0; j < 8; ++j) ones[j] = (__bf16)1.0f;

    f32x4 l_acc[4] = {};
    f32x4 o_acc[4][4] = {};   // [dt][rt]

    // ---- staging (8 DMA instr / wave / tile) ----
    const int lr3 = lane >> 3, lc3 = lane & 7;     // K: row-in-chunk, col-chunk
    const int lr4 = lane >> 4, lc4 = lane & 15;    // V: row-in-chunk, col-chunk
    // K: LDS[row][x] = K[row][x ^ ((row&7)<<4)]; row&7 == lr3 here
    const int kcol = ((lc3 ^ lr3) << 4);
    const char* Kg = (const char*)(Kb + (head * NPIX) * HD);
    const char* Vg = (const char*)(Vb + (head * HD) * NPIX);

    auto stageK = [&](int it, int b) {
        char* dst = smem + (b ? OFFK1 : OFFK0) + wave * 4096;  // wave's 32 rows
        const char* src = Kg + (it * 128 + wave * 32) * 128;   // 128 B / K-row
        #pragma unroll
        for (int i = 0; i < 4; ++i)
            gload_lds16(src + (i * 8 + lr3) * 128 + kcol, dst + i * 1024);
    };
    auto stageV = [&](int it, int b) {
        char* dst = smem + (b ? OFFV1 : OFFV0) + wave * 4096;  // wave's 16 d-rows
        const char* src = Vg + (wave * 16) * (NPIX * 2) + it * 256;  // 256 B/tile-row
        #pragma unroll
        for (int i = 0; i < 4; ++i) {
            const int d  = i * 4 + lr4;                 // d-row within wave's 16
            const int sw = (((wave * 16 + d) & 7) << 4);
            gload_lds16(src + d * (NPIX * 2) + ((lc4 << 4) ^ sw), dst + i * 1024);
        }
    };

    // S^T = K Q^T : C(key_local = kt*16+quad*4+r, row = rt*16+l16)
    auto qk = [&](bf16x8 k0, bf16x8 k1, bf16x8 k2, bf16x8 k3,
                  f32x4 (&s0)[4], f32x4 (&s1)[4]) {
        #pragma unroll
        for (int rt = 0; rt < 4; ++rt) {
            s0[rt] = f32x4{0.f, 0.f, 0.f, 0.f};
            s1[rt] = f32x4{0.f, 0.f, 0.f, 0.f};
            s0[rt] = __builtin_amdgcn_mfma_f32_16x16x32_bf16(k0, qf[rt][0], s0[rt], 0, 0, 0);
            s0[rt] = __builtin_amdgcn_mfma_f32_16x16x32_bf16(k1, qf[rt][1], s0[rt], 0, 0, 0);
            s1[rt] = __builtin_amdgcn_mfma_f32_16x16x32_bf16(k2, qf[rt][0], s1[rt], 0, 0, 0);
            s1[rt] = __builtin_amdgcn_mfma_f32_16x16x32_bf16(k3, qf[rt][1], s1[rt], 0, 0, 0);
        }
    };

    auto pvx = [&](const f32x4 (&s0)[4], const f32x4 (&s1)[4],
                   bf16x8 v0, bf16x8 v1, bf16x8 v2, bf16x8 v3) {
        #pragma unroll
        for (int rt = 0; rt < 4; ++rt) {
            unsigned a0 = pack_bf16x2(EXP2(s0[rt][0]), EXP2(s0[rt][1]));
            unsigned a1 = pack_bf16x2(EXP2(s0[rt][2]), EXP2(s0[rt][3]));
            unsigned b0 = pack_bf16x2(EXP2(s1[rt][0]), EXP2(s1[rt][1]));
            unsigned b1 = pack_bf16x2(EXP2(s1[rt][2]), EXP2(s1[rt][3]));
            // swap32 then swap16: (a0,b0) -> (w0,w2); (a1,b1) -> (w1,w3)
            asm("v_permlane32_swap_b32 %0, %1" : "+v"(a0), "+v"(b0));
            asm("v_permlane32_swap_b32 %0, %1" : "+v"(a1), "+v"(b1));
            asm("v_permlane16_swap_b32 %0, %1" : "+v"(a0), "+v"(b0));
            asm("v_permlane16_swap_b32 %0, %1" : "+v"(a1), "+v"(b1));
            uint32x4 w;
            w[0] = a0; w[1] = a1; w[2] = b0; w[3] = b1;
            const bf16x8 bp = __builtin_bit_cast(bf16x8, w);  // B[k=key32][n=row]
            l_acc[rt] = __builtin_amdgcn_mfma_f32_16x16x32_bf16(ones, bp, l_acc[rt], 0, 0, 0);
            o_acc[0][rt] = __builtin_amdgcn_mfma_f32_16x16x32_bf16(v0, bp, o_acc[0][rt], 0, 0, 0);
            o_acc[1][rt] = __builtin_amdgcn_mfma_f32_16x16x32_bf16(v1, bp, o_acc[1][rt], 0, 0, 0);
            o_acc[2][rt] = __builtin_amdgcn_mfma_f32_16x16x32_bf16(v2, bp, o_acc[2][rt], 0, 0, 0);
            o_acc[3][rt] = __builtin_amdgcn_mfma_f32_16x16x32_bf16(v3, bp, o_acc[3][rt], 0, 0, 0);
        }
    };

    // prologue: tiles 0 and 1 in flight (16 DMAs)
    stageK(0, 0); stageV(0, 0);
    stageK(1, 1); stageV(1, 1);

    const int ksw = ((l16 & 7) << 4);

    #pragma unroll 1
    for (int it = 0; it < 32; ++it) {
        const int b = it & 1;
        if (it == 31) asm volatile("s_waitcnt vmcnt(0)" ::: "memory");
        else          asm volatile("s_waitcnt vmcnt(8)" ::: "memory");
        __builtin_amdgcn_s_barrier();            // all waves' tile-it staged
        __builtin_amdgcn_sched_barrier(0);

        const char* bk = smem + (b ? OFFK1 : OFFK0);
        const char* bv = smem + (b ? OFFV1 : OFFV0);

        // K frags (swizzled read; wave's own 32 rows)
        const int kr0 = (wave * 32 + l16) * 128;
        bf16x8 k0 = *(const bf16x8*)(bk + kr0 + ((quad * 16) ^ ksw));
        bf16x8 k1 = *(const bf16x8*)(bk + kr0 + ((64 + quad * 16) ^ ksw));
        bf16x8 k2 = *(const bf16x8*)(bk + kr0 + 2048 + ((quad * 16) ^ ksw));
        bf16x8 k3 = *(const bf16x8*)(bk + kr0 + 2048 + ((64 + quad * 16) ^ ksw));
        // V frags (swizzled read; all 64 d-rows, wave's 64B key slice)
        const int vcol = (wave * 64 + quad * 16) ^ ksw;
        bf16x8 v0 = *(const bf16x8*)(bv + (l16) * 256 + vcol);
        bf16x8 v1 = *(const bf16x8*)(bv + (16 + l16) * 256 + vcol);
        bf16x8 v2 = *(const bf16x8*)(bv + (32 + l16) * 256 + vcol);
        bf16x8 v3 = *(const bf16x8*)(bv + (48 + l16) * 256 + vcol);

        f32x4 s0[4], s1[4];
        qk(k0, k1, k2, k3, s0, s1);
        pvx(s0, s1, v0, v1, v2, v3);

        __builtin_amdgcn_sched_barrier(0);
        __builtin_amdgcn_s_barrier();            // all waves done reading buf
        if (it < 30) { stageK(it + 2, b); stageV(it + 2, b); }
    }

    // ---- in-LDS 4-way key merge (overlay over the K/V buffers) ----
    float* co = (float*)smem;
    float* cl = (float*)(smem + 69632);

    #pragma unroll
    for (int dt = 0; dt < 4; ++dt)
        #pragma unroll
        for (int rt = 0; rt < 4; ++rt)
            *(f32x4*)(co + wave * 4352 + (rt * 16 + l16) * 68 + dt * 16 + quad * 4) = o_acc[dt][rt];
    if (quad == 0) {
        #pragma unroll
        for (int rt = 0; rt < 4; ++rt)
            cl[wave * 64 + rt * 16 + l16] = l_acc[rt][0];
    }
    __syncthreads();

    {
        const int row = t >> 2, dc = (t & 3) * 16;
        const float l = cl[row] + cl[64 + row] + cl[128 + row] + cl[192 + row];
        const float inv = 1.f / l;
        f32x4 s[4];
        #pragma unroll
        for (int j = 0; j < 4; ++j) {
            s[j] = f32x4{0.f, 0.f, 0.f, 0.f};
            #pragma unroll
            for (int w = 0; w < 4; ++w)
                s[j] += *(const f32x4*)(co + w * 4352 + row * 68 + dc + j * 4);
        }
        bf16x8 o1, o2;
        #pragma unroll
        for (int j = 0; j < 4; ++j) {
            o1[j]     = (__bf16)(s[0][j] * inv);
            o1[j + 4] = (__bf16)(s[1][j] * inv);
            o2[j]     = (__bf16)(s[2][j] * inv);
            o2[j + 4] = (__bf16)(s[3][j] * inv);
        }
        __bf16* dst = Sb + (p0 + row) * CCH + head * HD + dc;
        *(bf16x8*)(dst)     = o1;
        *(bf16x8*)(dst + 8) = o2;
    }
}

// ---------------------------------------------------------------------------
// K3: proj bf16 MFMA GEMM + bias + residual, fp32 out [c][pix].
// (unchanged from R12)
// ---------------------------------------------------------------------------
__global__ __launch_bounds__(256) void gemm_proj(
    const __bf16* __restrict__ Sb, const __bf16* __restrict__ Wpb,
    const float* __restrict__ bias, const float* __restrict__ X,
    float* __restrict__ Out)
{
    __shared__ __bf16 Bs[32 * XPITCH];

    const int t = threadIdx.x, lane = t & 63, wave = t >> 6;
    const int l16 = lane & 15, quad = lane >> 4;
    const int p0  = blockIdx.x * 32;
    const int och = blockIdx.y;

    #pragma unroll
    for (int pg = 0; pg < 4; ++pg) {
        bf16x8 v = *(const bf16x8*)(Sb + t * NPIX + p0 + pg * 8);
        #pragma unroll
        for (int j = 0; j < 8; ++j)
            Bs[(pg * 8 + j) * XPITCH + t] = v[j];
    }
    __syncthreads();

    const int pixset = wave & 1, ocset = wave >> 1;
    bf16x8 af[8];
    #pragma unroll
    for (int kc = 0; kc < 8; ++kc)
        af[kc] = *(const bf16x8*)(Bs + (pixset * 16 + l16) * XPITCH + kc * 32 + quad * 8);

    #pragma unroll
    for (int u = 0; u < 4; ++u) {
        f32x4 acc = {};
        const int oc_t = och * 128 + ocset * 64 + u * 16;
        #pragma unroll
        for (int kc = 0; kc < 8; ++kc) {
            bf16x8 wf = *(const bf16x8*)(Wpb + (oc_t + l16) * CCH + kc * 32 + quad * 8);
            acc = __builtin_amdgcn_mfma_f32_16x16x32_bf16(af[kc], wf, acc, 0, 0, 0);
        }
        const int oc  = oc_t + l16;
        const int pix = p0 + pixset * 16 + quad * 4;
        const float bz = bias[oc];
        f32x4 r4 = *(const f32x4*)(X + oc * NPIX + pix);
        f32x4 y;
        y[0] = acc[0] + bz + r4[0];
        y[1] = acc[1] + bz + r4[1];
        y[2] = acc[2] + bz + r4[2];
        y[3] = acc[3] + bz + r4[3];
        *(f32x4*)(Out + oc * NPIX + pix) = y;
    }
}

// ---------------------------------------------------------------------------
extern "C" void kernel_launch(void* const* d_in, const int* in_sizes, int n_in,
                              void* d_out, int out_size, void* d_ws, size_t ws_size,
                              hipStream_t stream)
{
    const float* x     = (const float*)d_in[0];
    const float* gamma = (const float*)d_in[1];
    const float* beta  = (const float*)d_in[2];
    const float* Wq    = (const float*)d_in[3];
    const float* bq    = (const float*)d_in[4];
    const float* Wk    = (const float*)d_in[5];
    const float* bk    = (const float*)d_in[6];
    const float* Wv    = (const float*)d_in[7];
    const float* bv    = (const float*)d_in[8];
    const float* Wp    = (const float*)d_in[9];
    const float* bp    = (const float*)d_in[10];
    float* out = (float*)d_out;

    char* ws = (char*)d_ws;
    float*  psum = (float*)(ws);                // 1KB stats partial sums
    float*  pssq = (float*)(ws + 1024);         // 1KB
    __bf16* Wb   = (__bf16*)(ws + 65536);       // 512KB bf16 4x[256][256]
    __bf16* Qb   = (__bf16*)(ws + (1 << 20));   // 2MB bf16 [head][pix][64]
    __bf16* Kb   = (__bf16*)(ws + (3 << 20));   // 2MB bf16 [head][pix][64]
    __bf16* Vb   = (__bf16*)(ws + (5 << 20));   // 2MB bf16 [c][pix]
    __bf16* Sb   = (__bf16*)(ws + (7 << 20));   // 2MB bf16 flat F

    stats_wconv<<<320, 256, 0, stream>>>(x, Wq, Wk, Wv, Wp, psum, pssq, Wb);

    dim3 gq(64, 6);
    gn_qkv<<<gq, 256, 0, stream>>>(x, gamma, beta, psum, pssq, Wb,
                                   bq, bk, bv, Qb, Kb, Vb);

    attn_mfma<<<256, 256, 0, stream>>>(Qb, Kb, Vb, Sb);

    dim3 gp(128, 2);
    gemm_proj<<<gp, 256, 0, stream>>>(Sb, Wb + 3 * 65536, bp, x, out);
}